// Round 13
// baseline (129.304 us; speedup 1.0000x reference)
//
#include <hip/hip_runtime.h>

using bf16x8 = __attribute__((ext_vector_type(8))) short;
using f32x4  = __attribute__((ext_vector_type(4))) float;

// ---- bf16 helpers (RNE) ----------------------------------------------------
__device__ __forceinline__ short f2bf(float x) {
    union { float f; unsigned u; } v; v.f = x;
    unsigned r = v.u + 0x7fffu + ((v.u >> 16) & 1u);
    return (short)(r >> 16);
}
__device__ __forceinline__ float bf2f(short h) {
    union { unsigned u; float f; } v; v.u = ((unsigned)(unsigned short)h) << 16;
    return v.f;
}

// ---------------------------------------------------------------------------
// Pack Wself/Wneigh (fp32, [DIN][256] each) into MFMA B-fragment order,
// bf16 hi only.  blk = ks*16+nt:  Wp[blk*512 + l*8] = frag (8 bf16).
// B-frag: lane l holds B[k = ks*32 + (l>>4)*8 + e][n = nt*16 + (l&15)]
// ---------------------------------------------------------------------------
template<int DIN>
__device__ __forceinline__ void pack_one(int blk, const float* __restrict__ Wself,
                                         const float* __restrict__ Wneigh,
                                         short* __restrict__ Wp, int l)
{
    const int ks  = blk >> 4, nt = blk & 15;
    const int col = nt * 16 + (l & 15);
    const int k0  = ks * 32 + (l >> 4) * 8;

    bf16x8 hi;
    #pragma unroll
    for (int e = 0; e < 8; ++e) {
        int k = k0 + e;
        float w = (k < DIN) ? Wself[k * 256 + col] : Wneigh[(k - DIN) * 256 + col];
        hi[e] = f2bf(w);
    }
    *reinterpret_cast<bf16x8*>(Wp + (size_t)blk * 512 + l * 8) = hi;
}

// ---------------------------------------------------------------------------
// Fused prep (single node, NO prior clear needed): demand-mark + weight-pack.
// Mark-only mask semantics: mask[i]==1 => compute row i. k_prep writes 1 to
// every NEEDED entry each call; unneeded entries hold poison/garbage and a
// spurious 1 only computes a correct-but-unused row (benign). Marked set is
// input-determined => deterministic output.
// ---------------------------------------------------------------------------
__global__ __launch_bounds__(256)
void k_prep(const int* __restrict__ neigh1, const int* __restrict__ neigh2,
            unsigned char* __restrict__ mask0, unsigned char* __restrict__ mask1,
            const float* __restrict__ Ws0, const float* __restrict__ Wn0,
            short* __restrict__ Wp0,
            const float* __restrict__ Ws1, const float* __restrict__ Wn1,
            short* __restrict__ Wp1)
{
    const int b = blockIdx.x, tid = threadIdx.x;
    if (b < 240) {
        int j = b * 256 + tid;                 // j < 61440 exactly
        mask0[neigh1[j]] = 1;
    } else if (b < 264) {
        int i = (b - 240) * 256 + tid;         // i < 6144 exactly
        mask0[i] = 1;
    } else if (b < 284) {
        int j = (b - 264) * 256 + tid;         // j < 5120 exactly
        mask1[neigh2[j]] = 1;
    } else if (b < 288) {
        int i = (b - 284) * 256 + tid;         // i < 1024 exactly
        mask1[i] = 1;
    } else {
        int unit = (b - 288) * 4 + (tid >> 6); // 384 units
        int l = tid & 63;
        if (unit < 128) pack_one<128>(unit, Ws0, Wn0, Wp0, l);
        else            pack_one<256>(unit - 128, Ws1, Wn1, Wp1, l);
    }
}

// ---------------------------------------------------------------------------
// Fused SAGE layer, bf16 MFMA (16x16x32), DOUT=256.
// Validated phase structure: nb(+need) -> barrier -> gather-mean -> barrier ->
// single k-loop GEMM -> epilogue.
// R13: An stored as bf16 in LDS (bit-identical: GEMM consumed f2bf(An) anyway;
//      halves LDS, neighbor half of GEMM becomes direct ds_read_b128).
//      Self-row loads predicated on need[] (unneeded rows: ah=0, row-isolated
//      in MFMA, never stored).
//   MASKED:   per-row demand predication via byte mask.
//   IN_BF16:  input features are bf16
//   OUT_BF16: write output as bf16
// ---------------------------------------------------------------------------
template<int DIN, int F, int RB, int NTW, bool MASKED, bool IN_BF16, bool OUT_BF16, bool RELU>
__global__ __launch_bounds__(256)
void sage_mfma(const void* __restrict__ h_in_v,
               const int*   __restrict__ neigh,
               const short* __restrict__ Wp,
               const float* __restrict__ bias,
               void* __restrict__ h_out_v,
               const unsigned char* __restrict__ mask)
{
    constexpr int KS    = DIN / 16;         // k-steps over Ktot = 2*DIN (32 each)
    constexpr int KSH   = DIN / 32;         // self-half k-steps
    constexpr int LROWB = DIN + 8;          // bf16 row stride (272B/528B: 2-way banks, free)
    constexpr int WROWS = RB / 16;
    constexpr int WCOLS = 16 / NTW;
    static_assert(WROWS * WCOLS == 4, "4 waves");
    constexpr float invF = 1.0f / F;

    __shared__ short         An[RB][LROWB]; // mean of neighbor rows (bf16)
    __shared__ int           nb[RB * F];
    __shared__ unsigned char need[RB];

    const int  tid = threadIdx.x;
    const int  w   = tid >> 6, l = tid & 63;
    const int  lr  = l & 15, lk = l >> 4;
    const long r0  = (long)blockIdx.x * RB;
    const int  wrow = (w % WROWS) * 16;
    const int  nt0  = (w / WROWS) * NTW;

    for (int p = tid; p < RB * F; p += 256)
        nb[p] = neigh[r0 * F + p];
    if constexpr (MASKED) {
        for (int p = tid; p < RB; p += 256)
            need[p] = mask[r0 + p];
    }
    __syncthreads();                        // nb (+need) ready

    if constexpr (!IN_BF16) {
        // ---- gather + mean (fp32 rows), store bf16 ----
        constexpr int QD = DIN / 4;
        const float* hin = (const float*)h_in_v;
        for (int p = tid; p < RB * QD; p += 256) {
            int m = p / QD, q = p - m * QD;
            if (MASKED && need[m] != 1) continue;
            float4 a = make_float4(0.f, 0.f, 0.f, 0.f);
            #pragma unroll 5
            for (int n = 0; n < F; ++n) {
                long idx = nb[m * F + n];
                float4 v = reinterpret_cast<const float4*>(hin + idx * DIN)[q];
                a.x += v.x; a.y += v.y; a.z += v.z; a.w += v.w;
            }
            short4 s;
            s.x = f2bf(a.x * invF); s.y = f2bf(a.y * invF);
            s.z = f2bf(a.z * invF); s.w = f2bf(a.w * invF);
            *reinterpret_cast<short4*>(&An[m][q * 4]) = s;
        }
    } else {
        // ---- gather + mean (bf16 rows, fp32 accumulate), store bf16 ----
        constexpr int NQ = DIN / 8;
        const short* hin = (const short*)h_in_v;
        for (int p = tid; p < RB * NQ; p += 256) {
            int m = p / NQ, c = p - m * NQ;
            if (MASKED && need[m] != 1) continue;
            float a[8] = {0.f,0.f,0.f,0.f,0.f,0.f,0.f,0.f};
            #pragma unroll 5
            for (int n = 0; n < F; ++n) {
                long idx = nb[m * F + n];
                bf16x8 v = *reinterpret_cast<const bf16x8*>(hin + idx * DIN + c * 8);
                #pragma unroll
                for (int e = 0; e < 8; ++e) a[e] += bf2f(v[e]);
            }
            bf16x8 s;
            #pragma unroll
            for (int e = 0; e < 8; ++e) s[e] = f2bf(a[e] * invF);
            *reinterpret_cast<bf16x8*>(&An[m][c * 8]) = s;
        }
    }
    __syncthreads();                        // An ready

    // ---- GEMM: single k-loop, self half from global (need-predicated),
    //      neigh half as direct bf16 ds_read ----
    const bool  selfok   = !MASKED || (need[wrow + lr] == 1);
    const float* selfrowF = (const float*)h_in_v + (r0 + wrow + lr) * DIN;
    const short* selfrowB = (const short*)h_in_v + (r0 + wrow + lr) * DIN;
    const short* neighrow = &An[wrow + lr][0];

    f32x4 acc[NTW];
    #pragma unroll
    for (int j = 0; j < NTW; ++j) acc[j] = f32x4{0.f, 0.f, 0.f, 0.f};

    for (int ks = 0; ks < KS; ++ks) {
        bf16x8 ah;
        if (ks < KSH) {
            if (selfok) {
                if constexpr (IN_BF16) {
                    ah = *reinterpret_cast<const bf16x8*>(selfrowB + ks * 32 + lk * 8);
                } else {
                    const int k0 = ks * 32 + lk * 8;
                    float4 t0 = *reinterpret_cast<const float4*>(selfrowF + k0);
                    float4 t1 = *reinterpret_cast<const float4*>(selfrowF + k0 + 4);
                    ah[0] = f2bf(t0.x); ah[1] = f2bf(t0.y);
                    ah[2] = f2bf(t0.z); ah[3] = f2bf(t0.w);
                    ah[4] = f2bf(t1.x); ah[5] = f2bf(t1.y);
                    ah[6] = f2bf(t1.z); ah[7] = f2bf(t1.w);
                }
            } else {
                #pragma unroll
                for (int e = 0; e < 8; ++e) ah[e] = 0;
            }
        } else {
            ah = *reinterpret_cast<const bf16x8*>(neighrow + (ks - KSH) * 32 + lk * 8);
        }

        // compact Wp: 64 bf16x8 frags per (ks,nt) block
        const bf16x8* wp = reinterpret_cast<const bf16x8*>(Wp) +
                           (size_t)(ks * 16 + nt0) * 64;
        #pragma unroll
        for (int j = 0; j < NTW; ++j) {
            bf16x8 bh = wp[j * 64 + l];
            acc[j] = __builtin_amdgcn_mfma_f32_16x16x32_bf16(ah, bh, acc[j], 0, 0, 0);
        }
    }

    // ---- epilogue: bias (+relu); C/D: col=l&15, row=(l>>4)*4+r ----
    #pragma unroll
    for (int j = 0; j < NTW; ++j) {
        const int col = (nt0 + j) * 16 + lr;
        const float b = bias[col];
        #pragma unroll
        for (int r = 0; r < 4; ++r) {
            const int slot = wrow + lk * 4 + r;
            if (MASKED && need[slot] != 1) continue;
            const long row = r0 + slot;
            float val = acc[j][r] + b;
            if (RELU) val = fmaxf(val, 0.f);
            if constexpr (OUT_BF16)
                ((short*)h_out_v)[row * 256 + col] = f2bf(val);
            else
                ((float*)h_out_v)[row * 256 + col] = val;
        }
    }
}

// ---------------------------------------------------------------------------
// Final layer: M=1024, DIN=256, F=5, DOUT=47, fp32 vector math.
// 4-way accumulator split for ILP (fp32 chain is otherwise serial).
// ---------------------------------------------------------------------------
__global__ __launch_bounds__(64)
void sage_out(const float* __restrict__ h_in,
              const int*   __restrict__ neigh,
              const float* __restrict__ Wself,
              const float* __restrict__ Wneigh,
              const float* __restrict__ bias,
              float* __restrict__ out)
{
    __shared__ float hs[256], hn[256];
    __shared__ int   nb[5];
    const int r = blockIdx.x, tid = threadIdx.x;

    if (tid < 5) nb[tid] = neigh[r * 5 + tid];
    __syncthreads();

    for (int k = tid; k < 256; k += 64) {
        hs[k] = h_in[(long)r * 256 + k];
        float a = 0.f;
        #pragma unroll
        for (int n = 0; n < 5; ++n) a += h_in[(long)nb[n] * 256 + k];
        hn[k] = a * 0.2f;
    }
    __syncthreads();

    if (tid < 47) {
        float a0 = 0.f, a1 = 0.f, a2 = 0.f, a3 = 0.f;
        #pragma unroll 4
        for (int k = 0; k < 256; k += 4) {
            a0 += hs[k    ] * Wself[(k    ) * 47 + tid] + hn[k    ] * Wneigh[(k    ) * 47 + tid];
            a1 += hs[k + 1] * Wself[(k + 1) * 47 + tid] + hn[k + 1] * Wneigh[(k + 1) * 47 + tid];
            a2 += hs[k + 2] * Wself[(k + 2) * 47 + tid] + hn[k + 2] * Wneigh[(k + 2) * 47 + tid];
            a3 += hs[k + 3] * Wself[(k + 3) * 47 + tid] + hn[k + 3] * Wneigh[(k + 3) * 47 + tid];
        }
        out[r * 47 + tid] = bias[tid] + ((a0 + a1) + (a2 + a3));
    }
}

// ---------------------------------------------------------------------------
extern "C" void kernel_launch(void* const* d_in, const int* in_sizes, int n_in,
                              void* d_out, int out_size, void* d_ws, size_t ws_size,
                              hipStream_t stream)
{
    const float* x   = (const float*)d_in[0];
    const int*   n0  = (const int*)  d_in[1];
    const int*   n1  = (const int*)  d_in[2];
    const int*   n2  = (const int*)  d_in[3];
    const float* Ws0 = (const float*)d_in[4];
    const float* Wn0 = (const float*)d_in[5];
    const float* b0  = (const float*)d_in[6];
    const float* Ws1 = (const float*)d_in[7];
    const float* Wn1 = (const float*)d_in[8];
    const float* b1  = (const float*)d_in[9];
    const float* Ws2 = (const float*)d_in[10];
    const float* Wn2 = (const float*)d_in[11];
    const float* b2  = (const float*)d_in[12];
    float* out = (float*)d_out;

    // workspace layout
    short*         h1    = (short*)d_ws;                          // 67584*256 bf16 = 34.6 MB
    float*         h2    = (float*)(h1 + (size_t)67584 * 256);    //  6144*256 f32  =  6.3 MB
    short*         Wp0   = (short*)(h2 + (size_t)6144 * 256);     // 128*512 bf16 = 128 KB
    short*         Wp1   = Wp0 + (size_t)128 * 512;               // 256*512 bf16 = 256 KB
    unsigned char* mask0 = (unsigned char*)(Wp1 + (size_t)256 * 512); // 67584 B
    unsigned char* mask1 = mask0 + 67584;                         // 6144 B

    constexpr int M0 = 67584;

    // node 1: fused prep — demand marks for h1 & h2 + W packs
    k_prep<<<384, 256, 0, stream>>>(n1, n2, mask0, mask1,
                                    Ws0, Wn0, Wp0, Ws1, Wn1, Wp1);

    // node 2: layer 0 — fp32 in, bf16 out; demand-masked rows
    sage_mfma<128, 15, 32, 8, true,  false, true,  true>
        <<<M0 / 32, 256, 0, stream>>>(x,  n0, Wp0, b0, h1, mask0);

    // node 3: layer 1 — bf16 in, fp32 out; demand-masked rows
    sage_mfma<256, 10, 16, 4, true,  true,  false, true>
        <<<6144 / 16, 256, 0, stream>>>(h1, n1, Wp1, b1, h2, mask1);

    // node 4: layer 2
    sage_out<<<1024, 64, 0, stream>>>(h2, n2, Ws2, Wn2, b2, out);
}

// Round 15
// 128.502 us; speedup vs baseline: 1.0062x; 1.0062x over previous
//
#include <hip/hip_runtime.h>

using bf16x8 = __attribute__((ext_vector_type(8))) short;
using f32x4  = __attribute__((ext_vector_type(4))) float;

// ---- bf16 helpers (RNE) ----------------------------------------------------
__device__ __forceinline__ short f2bf(float x) {
    union { float f; unsigned u; } v; v.f = x;
    unsigned r = v.u + 0x7fffu + ((v.u >> 16) & 1u);
    return (short)(r >> 16);
}
__device__ __forceinline__ float bf2f(short h) {
    union { unsigned u; float f; } v; v.u = ((unsigned)(unsigned short)h) << 16;
    return v.f;
}

// ---------------------------------------------------------------------------
// Pack Wself/Wneigh (fp32, [DIN][256] each) into MFMA B-fragment order,
// bf16 hi only.  blk = ks*16+nt:  Wp[blk*512 + l*8] = frag (8 bf16).
// B-frag: lane l holds B[k = ks*32 + (l>>4)*8 + e][n = nt*16 + (l&15)]
// ---------------------------------------------------------------------------
template<int DIN>
__device__ __forceinline__ void pack_one(int blk, const float* __restrict__ Wself,
                                         const float* __restrict__ Wneigh,
                                         short* __restrict__ Wp, int l)
{
    const int ks  = blk >> 4, nt = blk & 15;
    const int col = nt * 16 + (l & 15);
    const int k0  = ks * 32 + (l >> 4) * 8;

    bf16x8 hi;
    #pragma unroll
    for (int e = 0; e < 8; ++e) {
        int k = k0 + e;
        float w = (k < DIN) ? Wself[k * 256 + col] : Wneigh[(k - DIN) * 256 + col];
        hi[e] = f2bf(w);
    }
    *reinterpret_cast<bf16x8*>(Wp + (size_t)blk * 512 + l * 8) = hi;
}

// ---------------------------------------------------------------------------
// Fused prep (single node, NO prior clear needed): demand-mark + weight-pack.
// Mark-only mask semantics: mask[i]==1 => compute row i. k_prep writes 1 to
// every NEEDED entry each call; unneeded entries hold poison/garbage and a
// spurious 1 only computes a correct-but-unused row (benign). Marked set is
// input-determined => deterministic output.
// ---------------------------------------------------------------------------
__global__ __launch_bounds__(256)
void k_prep(const int* __restrict__ neigh1, const int* __restrict__ neigh2,
            unsigned char* __restrict__ mask0, unsigned char* __restrict__ mask1,
            const float* __restrict__ Ws0, const float* __restrict__ Wn0,
            short* __restrict__ Wp0,
            const float* __restrict__ Ws1, const float* __restrict__ Wn1,
            short* __restrict__ Wp1)
{
    const int b = blockIdx.x, tid = threadIdx.x;
    if (b < 240) {
        int j = b * 256 + tid;                 // j < 61440 exactly
        mask0[neigh1[j]] = 1;
    } else if (b < 264) {
        int i = (b - 240) * 256 + tid;         // i < 6144 exactly
        mask0[i] = 1;
    } else if (b < 284) {
        int j = (b - 264) * 256 + tid;         // j < 5120 exactly
        mask1[neigh2[j]] = 1;
    } else if (b < 288) {
        int i = (b - 284) * 256 + tid;         // i < 1024 exactly
        mask1[i] = 1;
    } else {
        int unit = (b - 288) * 4 + (tid >> 6); // 384 units
        int l = tid & 63;
        if (unit < 128) pack_one<128>(unit, Ws0, Wn0, Wp0, l);
        else            pack_one<256>(unit - 128, Ws1, Wn1, Wp1, l);
    }
}

// ---------------------------------------------------------------------------
// Fused SAGE layer, bf16 MFMA (16x16x32), DOUT=256.
// Validated phase structure: nb(+need) -> barrier -> gather-mean -> barrier ->
// single k-loop GEMM -> epilogue.  (R12-validated source, reverted to after
// the R14 cooperative experiment failed to launch.)
//   MASKED:   per-row demand predication via byte mask.
//   IN_BF16:  input features are bf16 (exact A-frags from memory)
//   OUT_BF16: write output as bf16
// ---------------------------------------------------------------------------
template<int DIN, int F, int RB, int NTW, bool MASKED, bool IN_BF16, bool OUT_BF16, bool RELU>
__global__ __launch_bounds__(256)
void sage_mfma(const void* __restrict__ h_in_v,
               const int*   __restrict__ neigh,
               const short* __restrict__ Wp,
               const float* __restrict__ bias,
               void* __restrict__ h_out_v,
               const unsigned char* __restrict__ mask)
{
    constexpr int KS    = DIN / 16;         // k-steps over Ktot = 2*DIN (32 each)
    constexpr int KSH   = DIN / 32;         // self-half k-steps
    constexpr int LROW  = DIN + 4;
    constexpr int WROWS = RB / 16;
    constexpr int WCOLS = 16 / NTW;
    static_assert(WROWS * WCOLS == 4, "4 waves");
    constexpr float invF = 1.0f / F;

    __shared__ float         An[RB][LROW];  // mean of neighbor rows (fp32)
    __shared__ int           nb[RB * F];
    __shared__ unsigned char need[RB];

    const int  tid = threadIdx.x;
    const int  w   = tid >> 6, l = tid & 63;
    const int  lr  = l & 15, lk = l >> 4;
    const long r0  = (long)blockIdx.x * RB;
    const int  wrow = (w % WROWS) * 16;
    const int  nt0  = (w / WROWS) * NTW;

    for (int p = tid; p < RB * F; p += 256)
        nb[p] = neigh[r0 * F + p];
    if constexpr (MASKED) {
        for (int p = tid; p < RB; p += 256)
            need[p] = mask[r0 + p];
    }
    __syncthreads();                        // nb (+need) ready

    if constexpr (!IN_BF16) {
        // ---- gather + mean (fp32 rows) ----
        constexpr int QD = DIN / 4;
        const float* hin = (const float*)h_in_v;
        for (int p = tid; p < RB * QD; p += 256) {
            int m = p / QD, q = p - m * QD;
            if (MASKED && need[m] != 1) continue;
            float4 a = make_float4(0.f, 0.f, 0.f, 0.f);
            #pragma unroll 5
            for (int n = 0; n < F; ++n) {
                long idx = nb[m * F + n];
                float4 v = reinterpret_cast<const float4*>(hin + idx * DIN)[q];
                a.x += v.x; a.y += v.y; a.z += v.z; a.w += v.w;
            }
            a.x *= invF; a.y *= invF; a.z *= invF; a.w *= invF;
            *reinterpret_cast<float4*>(&An[m][q * 4]) = a;
        }
    } else {
        // ---- gather + mean (bf16 rows, fp32 accumulate) ----
        constexpr int NQ = DIN / 8;
        const short* hin = (const short*)h_in_v;
        for (int p = tid; p < RB * NQ; p += 256) {
            int m = p / NQ, c = p - m * NQ;
            if (MASKED && need[m] != 1) continue;
            float a[8] = {0.f,0.f,0.f,0.f,0.f,0.f,0.f,0.f};
            #pragma unroll 5
            for (int n = 0; n < F; ++n) {
                long idx = nb[m * F + n];
                bf16x8 v = *reinterpret_cast<const bf16x8*>(hin + idx * DIN + c * 8);
                #pragma unroll
                for (int e = 0; e < 8; ++e) a[e] += bf2f(v[e]);
            }
            #pragma unroll
            for (int e = 0; e < 8; ++e) a[e] *= invF;
            *reinterpret_cast<float4*>(&An[m][c * 8])     = make_float4(a[0],a[1],a[2],a[3]);
            *reinterpret_cast<float4*>(&An[m][c * 8 + 4]) = make_float4(a[4],a[5],a[6],a[7]);
        }
    }
    __syncthreads();                        // An ready

    // ---- GEMM: single k-loop, self half from global, neigh half from LDS ----
    const float* selfrowF = (const float*)h_in_v + (r0 + wrow + lr) * DIN;
    const short* selfrowB = (const short*)h_in_v + (r0 + wrow + lr) * DIN;
    const float* neighrow = &An[wrow + lr][0];

    f32x4 acc[NTW];
    #pragma unroll
    for (int j = 0; j < NTW; ++j) acc[j] = f32x4{0.f, 0.f, 0.f, 0.f};

    for (int ks = 0; ks < KS; ++ks) {
        bf16x8 ah;
        if (ks < KSH) {
            if constexpr (IN_BF16) {
                ah = *reinterpret_cast<const bf16x8*>(selfrowB + ks * 32 + lk * 8);
            } else {
                const int k0 = ks * 32 + lk * 8;
                float4 t0 = *reinterpret_cast<const float4*>(selfrowF + k0);
                float4 t1 = *reinterpret_cast<const float4*>(selfrowF + k0 + 4);
                ah[0] = f2bf(t0.x); ah[1] = f2bf(t0.y);
                ah[2] = f2bf(t0.z); ah[3] = f2bf(t0.w);
                ah[4] = f2bf(t1.x); ah[5] = f2bf(t1.y);
                ah[6] = f2bf(t1.z); ah[7] = f2bf(t1.w);
            }
        } else {
            const int k0 = (ks - KSH) * 32 + lk * 8;
            float4 t0 = *reinterpret_cast<const float4*>(neighrow + k0);
            float4 t1 = *reinterpret_cast<const float4*>(neighrow + k0 + 4);
            ah[0] = f2bf(t0.x); ah[1] = f2bf(t0.y);
            ah[2] = f2bf(t0.z); ah[3] = f2bf(t0.w);
            ah[4] = f2bf(t1.x); ah[5] = f2bf(t1.y);
            ah[6] = f2bf(t1.z); ah[7] = f2bf(t1.w);
        }

        // compact Wp: 64 bf16x8 frags per (ks,nt) block
        const bf16x8* wp = reinterpret_cast<const bf16x8*>(Wp) +
                           (size_t)(ks * 16 + nt0) * 64;
        #pragma unroll
        for (int j = 0; j < NTW; ++j) {
            bf16x8 bh = wp[j * 64 + l];
            acc[j] = __builtin_amdgcn_mfma_f32_16x16x32_bf16(ah, bh, acc[j], 0, 0, 0);
        }
    }

    // ---- epilogue: bias (+relu); C/D: col=l&15, row=(l>>4)*4+r ----
    #pragma unroll
    for (int j = 0; j < NTW; ++j) {
        const int col = (nt0 + j) * 16 + lr;
        const float b = bias[col];
        #pragma unroll
        for (int r = 0; r < 4; ++r) {
            const int slot = wrow + lk * 4 + r;
            if (MASKED && need[slot] != 1) continue;
            const long row = r0 + slot;
            float val = acc[j][r] + b;
            if (RELU) val = fmaxf(val, 0.f);
            if constexpr (OUT_BF16)
                ((short*)h_out_v)[row * 256 + col] = f2bf(val);
            else
                ((float*)h_out_v)[row * 256 + col] = val;
        }
    }
}

// ---------------------------------------------------------------------------
// Final layer: M=1024, DIN=256, F=5, DOUT=47, fp32 vector math.
// 4-way accumulator split for ILP (fp32 chain is otherwise serial).
// ---------------------------------------------------------------------------
__global__ __launch_bounds__(64)
void sage_out(const float* __restrict__ h_in,
              const int*   __restrict__ neigh,
              const float* __restrict__ Wself,
              const float* __restrict__ Wneigh,
              const float* __restrict__ bias,
              float* __restrict__ out)
{
    __shared__ float hs[256], hn[256];
    __shared__ int   nb[5];
    const int r = blockIdx.x, tid = threadIdx.x;

    if (tid < 5) nb[tid] = neigh[r * 5 + tid];
    __syncthreads();

    for (int k = tid; k < 256; k += 64) {
        hs[k] = h_in[(long)r * 256 + k];
        float a = 0.f;
        #pragma unroll
        for (int n = 0; n < 5; ++n) a += h_in[(long)nb[n] * 256 + k];
        hn[k] = a * 0.2f;
    }
    __syncthreads();

    if (tid < 47) {
        float a0 = 0.f, a1 = 0.f, a2 = 0.f, a3 = 0.f;
        #pragma unroll 4
        for (int k = 0; k < 256; k += 4) {
            a0 += hs[k    ] * Wself[(k    ) * 47 + tid] + hn[k    ] * Wneigh[(k    ) * 47 + tid];
            a1 += hs[k + 1] * Wself[(k + 1) * 47 + tid] + hn[k + 1] * Wneigh[(k + 1) * 47 + tid];
            a2 += hs[k + 2] * Wself[(k + 2) * 47 + tid] + hn[k + 2] * Wneigh[(k + 2) * 47 + tid];
            a3 += hs[k + 3] * Wself[(k + 3) * 47 + tid] + hn[k + 3] * Wneigh[(k + 3) * 47 + tid];
        }
        out[r * 47 + tid] = bias[tid] + ((a0 + a1) + (a2 + a3));
    }
}

// ---------------------------------------------------------------------------
extern "C" void kernel_launch(void* const* d_in, const int* in_sizes, int n_in,
                              void* d_out, int out_size, void* d_ws, size_t ws_size,
                              hipStream_t stream)
{
    const float* x   = (const float*)d_in[0];
    const int*   n0  = (const int*)  d_in[1];
    const int*   n1  = (const int*)  d_in[2];
    const int*   n2  = (const int*)  d_in[3];
    const float* Ws0 = (const float*)d_in[4];
    const float* Wn0 = (const float*)d_in[5];
    const float* b0  = (const float*)d_in[6];
    const float* Ws1 = (const float*)d_in[7];
    const float* Wn1 = (const float*)d_in[8];
    const float* b1  = (const float*)d_in[9];
    const float* Ws2 = (const float*)d_in[10];
    const float* Wn2 = (const float*)d_in[11];
    const float* b2  = (const float*)d_in[12];
    float* out = (float*)d_out;

    // workspace layout
    short*         h1    = (short*)d_ws;                          // 67584*256 bf16 = 34.6 MB
    float*         h2    = (float*)(h1 + (size_t)67584 * 256);    //  6144*256 f32  =  6.3 MB
    short*         Wp0   = (short*)(h2 + (size_t)6144 * 256);     // 128*512 bf16 = 128 KB
    short*         Wp1   = Wp0 + (size_t)128 * 512;               // 256*512 bf16 = 256 KB
    unsigned char* mask0 = (unsigned char*)(Wp1 + (size_t)256 * 512); // 67584 B
    unsigned char* mask1 = mask0 + 67584;                         // 6144 B

    constexpr int M0 = 67584;

    // node 1: fused prep — demand marks for h1 & h2 + W packs
    k_prep<<<384, 256, 0, stream>>>(n1, n2, mask0, mask1,
                                    Ws0, Wn0, Wp0, Ws1, Wn1, Wp1);

    // node 2: layer 0 — fp32 in, bf16 out; demand-masked rows
    sage_mfma<128, 15, 32, 8, true,  false, true,  true>
        <<<M0 / 32, 256, 0, stream>>>(x,  n0, Wp0, b0, h1, mask0);

    // node 3: layer 1 — bf16 in, fp32 out; demand-masked rows
    sage_mfma<256, 10, 16, 4, true,  true,  false, true>
        <<<6144 / 16, 256, 0, stream>>>(h1, n1, Wp1, b1, h2, mask1);

    // node 4: layer 2
    sage_out<<<1024, 64, 0, stream>>>(h2, n2, Ws2, Wn2, b2, out);
}